// Round 4
// baseline (933.224 us; speedup 1.0000x reference)
//
#include <hip/hip_runtime.h>
#include <stdint.h>

#define N_NODES 1024
#define C2v 64
#define EMB 64
#define ALPHA 0.2f
#define NEG_FILL (-1e12f)

typedef __attribute__((ext_vector_type(8))) short short8v;   // 8 bf16 in 4 VGPRs
typedef __attribute__((ext_vector_type(4))) float float4v;
typedef unsigned int u32;

static __device__ __forceinline__ short f2bf(float f) {
    unsigned u = __builtin_bit_cast(unsigned, f);
    u = (u + 0x7FFFu + ((u >> 16) & 1u)) >> 16;   // RNE
    return (short)(unsigned short)u;
}
static __device__ __forceinline__ u32 pack2bf(float a, float b) {
    return (u32)(unsigned short)f2bf(a) | ((u32)(unsigned short)f2bf(b) << 16);
}
static __device__ __forceinline__ void gload16(const float* g, float* l) {
    __builtin_amdgcn_global_load_lds(
        (const __attribute__((address_space(1))) u32*)g,
        (__attribute__((address_space(3))) u32*)l, 16, 0, 0);
}

// ===========================================================================
// FAST PATH
// k1: wx = x @ W (bf16 MFMA); write wxT[b][e][j] (bf16) to ws; compute
//     s[i,j] = lrelu(wx)·a, masked softmax -> att[i][j] (bf16) to ws.
// ===========================================================================
__global__ __launch_bounds__(256) void k_wx(const float* __restrict__ x,
                                            const float* __restrict__ adj,
                                            const float* __restrict__ W,
                                            const float* __restrict__ a,
                                            unsigned short* __restrict__ wxT,
                                            unsigned short* __restrict__ att) {
    __shared__ float xs[2][4096];     // 2 x 16KB: per-wave 4KB chunks, swizzled
    __shared__ float s_lds[N_NODES];
    __shared__ float red[8];

    const int i   = blockIdx.x;
    const int tid = threadIdx.x;
    const int w   = tid >> 6;
    const int l   = tid & 63;
    const int g   = l >> 4;
    const int m   = l & 15;

    // W as MFMA B-fragments
    short8v wfrag[4][2];
#pragma unroll
    for (int nt = 0; nt < 4; ++nt)
#pragma unroll
        for (int ks = 0; ks < 2; ++ks) {
            short8v v;
#pragma unroll
            for (int ii = 0; ii < 8; ++ii)
                v[ii] = f2bf(W[(ks * 32 + g * 8 + ii) * EMB + nt * 16 + m]);
            wfrag[nt][ks] = v;
        }
    float afrag[4];
#pragma unroll
    for (int nt = 0; nt < 4; ++nt) afrag[nt] = a[nt * 16 + m];

    const float* xi = x + (size_t)i * N_NODES * C2v;

    // stage j-tile jt into xs[buf]: wave w stages its own rows w*16..w*16+15.
    // LDS dest linear (gload_lds writes base+lane*16); source pre-swizzled so
    // LDS[row][slot] = x[row][(slot^(row&7))*4 ..], matching the swizzled read.
    auto STAGE = [&](int jt, int buf) {
#pragma unroll
        for (int q = 0; q < 4; ++q) {
            const int row  = w * 16 + q * 4 + g;          // row within 64-tile
            const int slot = m ^ (row & 7);               // 16B slot 0..15
            gload16(xi + (size_t)(jt * 64 + row) * C2v + slot * 4,
                    &xs[buf][w * 1024 + q * 256]);
        }
    };

    STAGE(0, 0);
#pragma unroll
    for (int jt = 0; jt < 16; ++jt) {
        const int buf = jt & 1;
        if (jt < 15) STAGE(jt + 1, buf ^ 1);
        if (jt < 15) { asm volatile("s_waitcnt vmcnt(4)" ::: "memory"); }
        else         { asm volatile("s_waitcnt vmcnt(0)" ::: "memory"); }
        __builtin_amdgcn_sched_barrier(0);

        const int j0 = jt * 64 + w * 16;
        float4v acc[4];
#pragma unroll
        for (int nt = 0; nt < 4; ++nt) acc[nt] = (float4v)0.0f;

#pragma unroll
        for (int ks = 0; ks < 2; ++ks) {
            const int slo = (ks * 8 + 2 * g) ^ (m & 7);
            const int shi = (ks * 8 + 2 * g + 1) ^ (m & 7);
            const float4v lo = *(const float4v*)&xs[buf][w * 1024 + m * 64 + slo * 4];
            const float4v hi = *(const float4v*)&xs[buf][w * 1024 + m * 64 + shi * 4];
            short8v afr;
            afr[0] = f2bf(lo[0]); afr[1] = f2bf(lo[1]);
            afr[2] = f2bf(lo[2]); afr[3] = f2bf(lo[3]);
            afr[4] = f2bf(hi[0]); afr[5] = f2bf(hi[1]);
            afr[6] = f2bf(hi[2]); afr[7] = f2bf(hi[3]);
#pragma unroll
            for (int nt = 0; nt < 4; ++nt)
                acc[nt] = __builtin_amdgcn_mfma_f32_16x16x32_bf16(
                    afr, wfrag[nt][ks], acc[nt], 0, 0, 0);
        }

        // wxT[b=i][e=nt*16+m][j0+g*4 .. +3]  (4 consecutive j per lane -> 8B store)
#pragma unroll
        for (int nt = 0; nt < 4; ++nt) {
            uint2 pk;
            pk.x = pack2bf(acc[nt][0], acc[nt][1]);
            pk.y = pack2bf(acc[nt][2], acc[nt][3]);
            *(uint2*)&wxT[((size_t)i * EMB + nt * 16 + m) * N_NODES + j0 + g * 4] = pk;
        }

        // s[j] = sum_e lrelu(wx[j,e]) * a[e]
#pragma unroll
        for (int r = 0; r < 4; ++r) {
            float v = 0.f;
#pragma unroll
            for (int nt = 0; nt < 4; ++nt) {
                float t = acc[nt][r];
                t = (t > 0.f) ? t : (ALPHA * t);
                v += t * afrag[nt];
            }
            v += __shfl_xor(v, 1);
            v += __shfl_xor(v, 2);
            v += __shfl_xor(v, 4);
            v += __shfl_xor(v, 8);
            if (m == 0) s_lds[j0 + g * 4 + r] = v;
        }
    }
    __syncthreads();

    // masked softmax over the 1024 entries
    const float* adjrow = adj + (size_t)i * N_NODES;
    float sc[4];
    float lmax = -3.4e38f;
#pragma unroll
    for (int q = 0; q < 4; ++q) {
        int j = tid + q * 256;
        float v = s_lds[j] + (adjrow[j] > 0.f ? 0.f : NEG_FILL);
        sc[q] = v;
        lmax = fmaxf(lmax, v);
    }
#pragma unroll
    for (int d = 1; d < 64; d <<= 1) lmax = fmaxf(lmax, __shfl_xor(lmax, d));
    if (l == 0) red[w] = lmax;
    __syncthreads();
    const float M = fmaxf(fmaxf(red[0], red[1]), fmaxf(red[2], red[3]));

    float ex[4];
    float lsum = 0.f;
#pragma unroll
    for (int q = 0; q < 4; ++q) {
        ex[q] = __expf(sc[q] - M);
        lsum += ex[q];
    }
#pragma unroll
    for (int d = 1; d < 64; d <<= 1) lsum += __shfl_xor(lsum, d);
    __syncthreads();
    if (l == 0) red[w] = lsum;
    __syncthreads();
    const float S = red[0] + red[1] + red[2] + red[3];
    const float inv = 1.0f / S;

    unsigned short* arow = att + (size_t)i * N_NODES;
#pragma unroll
    for (int q = 0; q < 4; ++q) {
        int j = tid + q * 256;
        arow[j] = (unsigned short)f2bf(ex[q] * inv);
    }
}

// ===========================================================================
// k2: out[b][i][e] = sum_j att[i][j] * wx[b][j][e] + bias[e]
// Pure bf16 GEMM; A (att) and B (wxT) fragments are contiguous 16B loads.
// ===========================================================================
__global__ __launch_bounds__(256) void k_out2(const unsigned short* __restrict__ wxT,
                                              const unsigned short* __restrict__ att,
                                              const float* __restrict__ bias,
                                              float* __restrict__ out) {
    const int hw = blockIdx.x;
    const int L  = (hw & 7) * 512 + (hw >> 3);   // XCD swizzle: same-b blocks together
    const int b  = L >> 2;
    const int it = L & 3;

    const int tid = threadIdx.x;
    const int w   = tid >> 6;
    const int l   = tid & 63;
    const int g   = l >> 4;
    const int m   = l & 15;

    const int i0 = it * 256 + w * 64;
    const size_t abase = (size_t)(i0 + m) * N_NODES;          // + mt*16*1024
    const size_t bbase = ((size_t)b * EMB + m) * N_NODES;     // + nt*16*1024

    float4v acc[4][4];
#pragma unroll
    for (int mt = 0; mt < 4; ++mt)
#pragma unroll
        for (int nt = 0; nt < 4; ++nt) acc[mt][nt] = (float4v)0.0f;

    for (int kt = 0; kt < 16; ++kt) {
#pragma unroll
        for (int ks = 0; ks < 2; ++ks) {
            const int jc = kt * 64 + ks * 32 + g * 8;
            short8v afr[4], bfr[4];
#pragma unroll
            for (int mt = 0; mt < 4; ++mt)
                afr[mt] = *(const short8v*)&att[abase + (size_t)mt * 16 * N_NODES + jc];
#pragma unroll
            for (int nt = 0; nt < 4; ++nt)
                bfr[nt] = *(const short8v*)&wxT[bbase + (size_t)nt * 16 * N_NODES + jc];
#pragma unroll
            for (int mt = 0; mt < 4; ++mt)
#pragma unroll
                for (int nt = 0; nt < 4; ++nt)
                    acc[mt][nt] = __builtin_amdgcn_mfma_f32_16x16x32_bf16(
                        afr[mt], bfr[nt], acc[mt][nt], 0, 0, 0);
        }
    }

    float bv[4];
#pragma unroll
    for (int nt = 0; nt < 4; ++nt) bv[nt] = bias[nt * 16 + m];

#pragma unroll
    for (int mt = 0; mt < 4; ++mt)
#pragma unroll
        for (int nt = 0; nt < 4; ++nt)
#pragma unroll
            for (int r = 0; r < 4; ++r) {
                const int i = i0 + mt * 16 + g * 4 + r;
                out[((size_t)b * N_NODES + i) * EMB + nt * 16 + m] = acc[mt][nt][r] + bv[nt];
            }
}

// ===========================================================================
// FALLBACK PATH (ws too small): round-1 kernels, known-correct.
// ===========================================================================
__global__ __launch_bounds__(256) void k_att_fb(const float* __restrict__ x,
                                                const float* __restrict__ adj,
                                                const float* __restrict__ W,
                                                const float* __restrict__ a,
                                                unsigned short* __restrict__ att) {
    __shared__ float s_lds[N_NODES];
    __shared__ float red[8];
    const int i = blockIdx.x, tid = threadIdx.x;
    const int w = tid >> 6, l = tid & 63, g = l >> 4, m = l & 15;
    short8v wfrag[4][2];
#pragma unroll
    for (int nt = 0; nt < 4; ++nt)
#pragma unroll
        for (int ks = 0; ks < 2; ++ks) {
            short8v v;
#pragma unroll
            for (int ii = 0; ii < 8; ++ii)
                v[ii] = f2bf(W[(ks * 32 + g * 8 + ii) * EMB + nt * 16 + m]);
            wfrag[nt][ks] = v;
        }
    float afrag[4];
#pragma unroll
    for (int nt = 0; nt < 4; ++nt) afrag[nt] = a[nt * 16 + m];
    const float* xi = x + (size_t)i * N_NODES * C2v;
    for (int jt = 0; jt < N_NODES / 64; ++jt) {
        const int j0 = jt * 64 + w * 16;
        float4v acc[4];
#pragma unroll
        for (int nt = 0; nt < 4; ++nt) acc[nt] = (float4v)0.0f;
#pragma unroll
        for (int ks = 0; ks < 2; ++ks) {
            const float* p = xi + (size_t)(j0 + m) * C2v + ks * 32 + g * 8;
            float4v lo = *(const float4v*)p;
            float4v hi = *(const float4v*)(p + 4);
            short8v afr;
            afr[0] = f2bf(lo[0]); afr[1] = f2bf(lo[1]);
            afr[2] = f2bf(lo[2]); afr[3] = f2bf(lo[3]);
            afr[4] = f2bf(hi[0]); afr[5] = f2bf(hi[1]);
            afr[6] = f2bf(hi[2]); afr[7] = f2bf(hi[3]);
#pragma unroll
            for (int nt = 0; nt < 4; ++nt)
                acc[nt] = __builtin_amdgcn_mfma_f32_16x16x32_bf16(afr, wfrag[nt][ks], acc[nt], 0, 0, 0);
        }
#pragma unroll
        for (int r = 0; r < 4; ++r) {
            float v = 0.f;
#pragma unroll
            for (int nt = 0; nt < 4; ++nt) {
                float t = acc[nt][r];
                t = (t > 0.f) ? t : (ALPHA * t);
                v += t * afrag[nt];
            }
            v += __shfl_xor(v, 1); v += __shfl_xor(v, 2);
            v += __shfl_xor(v, 4); v += __shfl_xor(v, 8);
            if (m == 0) s_lds[j0 + g * 4 + r] = v;
        }
    }
    __syncthreads();
    const float* adjrow = adj + (size_t)i * N_NODES;
    float sc[4]; float lmax = -3.4e38f;
#pragma unroll
    for (int q = 0; q < 4; ++q) {
        int j = tid + q * 256;
        float v = s_lds[j] + (adjrow[j] > 0.f ? 0.f : NEG_FILL);
        sc[q] = v; lmax = fmaxf(lmax, v);
    }
#pragma unroll
    for (int d = 1; d < 64; d <<= 1) lmax = fmaxf(lmax, __shfl_xor(lmax, d));
    if (l == 0) red[w] = lmax;
    __syncthreads();
    const float M = fmaxf(fmaxf(red[0], red[1]), fmaxf(red[2], red[3]));
    float ex[4]; float lsum = 0.f;
#pragma unroll
    for (int q = 0; q < 4; ++q) { ex[q] = __expf(sc[q] - M); lsum += ex[q]; }
#pragma unroll
    for (int d = 1; d < 64; d <<= 1) lsum += __shfl_xor(lsum, d);
    __syncthreads();
    if (l == 0) red[w] = lsum;
    __syncthreads();
    const float S = red[0] + red[1] + red[2] + red[3];
    const float inv = 1.0f / S;
    unsigned short* arow = att + (size_t)i * N_NODES;
#pragma unroll
    for (int q = 0; q < 4; ++q) {
        int j = tid + q * 256;
        arow[j] = (unsigned short)f2bf(ex[q] * inv);
    }
}

__global__ __launch_bounds__(256) void k_out_fb(const float* __restrict__ x,
                                                const unsigned short* __restrict__ att,
                                                const float* __restrict__ W,
                                                const float* __restrict__ bias,
                                                float* __restrict__ out) {
    __shared__ __attribute__((aligned(16))) short tmp_lds[256][72];
    const int hw = blockIdx.x;
    const int L  = (hw & 7) * 512 + (hw >> 3);
    const int b  = L >> 2;
    const int it = L & 3;
    const int tid = threadIdx.x;
    const int w = tid >> 6, l = tid & 63, g = l >> 4, m = l & 15;
    float4v acc[4][4];
#pragma unroll
    for (int mt = 0; mt < 4; ++mt)
#pragma unroll
        for (int nt = 0; nt < 4; ++nt) acc[mt][nt] = (float4v)0.0f;
    const float* xb = x + (size_t)b * N_NODES * C2v;
    for (int kt = 0; kt < 16; ++kt) {
        const int j0 = kt * 64;
        short8v afr[4][2];
#pragma unroll
    for (int mt = 0; mt < 4; ++mt)
#pragma unroll
            for (int ks = 0; ks < 2; ++ks) {
                const int row = it * 256 + w * 64 + mt * 16 + m;
                afr[mt][ks] = *(const short8v*)&att[(size_t)row * N_NODES + j0 + ks * 32 + g * 8];
            }
        short8v bfr[4][2];
#pragma unroll
        for (int nt = 0; nt < 4; ++nt)
#pragma unroll
            for (int ks = 0; ks < 2; ++ks) {
                short8v v;
#pragma unroll
                for (int ii = 0; ii < 8; ++ii) {
                    const int j = j0 + ks * 32 + g * 8 + ii;
                    v[ii] = f2bf(xb[(size_t)j * C2v + nt * 16 + m]);
                }
                bfr[nt][ks] = v;
            }
#pragma unroll
        for (int mt = 0; mt < 4; ++mt)
#pragma unroll
            for (int nt = 0; nt < 4; ++nt)
#pragma unroll
                for (int ks = 0; ks < 2; ++ks)
                    acc[mt][nt] = __builtin_amdgcn_mfma_f32_16x16x32_bf16(
                        afr[mt][ks], bfr[nt][ks], acc[mt][nt], 0, 0, 0);
    }
#pragma unroll
    for (int mt = 0; mt < 4; ++mt)
#pragma unroll
        for (int nt = 0; nt < 4; ++nt)
#pragma unroll
            for (int r = 0; r < 4; ++r)
                tmp_lds[w * 64 + mt * 16 + g * 4 + r][nt * 16 + m] = f2bf(acc[mt][nt][r]);
    __syncthreads();
    short8v wfrag[4][2];
#pragma unroll
    for (int nt = 0; nt < 4; ++nt)
#pragma unroll
        for (int ks = 0; ks < 2; ++ks) {
            short8v v;
#pragma unroll
            for (int ii = 0; ii < 8; ++ii)
                v[ii] = f2bf(W[(ks * 32 + g * 8 + ii) * EMB + nt * 16 + m]);
            wfrag[nt][ks] = v;
        }
    float bfrag[4];
#pragma unroll
    for (int nt = 0; nt < 4; ++nt) bfrag[nt] = bias[nt * 16 + m];
    float4v acc2[4][4];
#pragma unroll
    for (int mt = 0; mt < 4; ++mt)
#pragma unroll
        for (int nt = 0; nt < 4; ++nt) acc2[mt][nt] = (float4v)0.0f;
#pragma unroll
    for (int mt = 0; mt < 4; ++mt)
#pragma unroll
        for (int ks = 0; ks < 2; ++ks) {
            const short8v a2 = *(const short8v*)&tmp_lds[w * 64 + mt * 16 + m][ks * 32 + g * 8];
#pragma unroll
            for (int nt = 0; nt < 4; ++nt)
                acc2[mt][nt] = __builtin_amdgcn_mfma_f32_16x16x32_bf16(a2, wfrag[nt][ks], acc2[mt][nt], 0, 0, 0);
        }
#pragma unroll
    for (int mt = 0; mt < 4; ++mt)
#pragma unroll
        for (int nt = 0; nt < 4; ++nt)
#pragma unroll
            for (int r = 0; r < 4; ++r) {
                const int i = it * 256 + w * 64 + mt * 16 + g * 4 + r;
                out[((size_t)b * N_NODES + i) * EMB + nt * 16 + m] = acc2[mt][nt][r] + bfrag[nt];
            }
}

extern "C" void kernel_launch(void* const* d_in, const int* in_sizes, int n_in,
                              void* d_out, int out_size, void* d_ws, size_t ws_size,
                              hipStream_t stream) {
    const float* x    = (const float*)d_in[0];
    const float* adj  = (const float*)d_in[1];
    const float* W    = (const float*)d_in[2];
    const float* a    = (const float*)d_in[3];
    const float* bias = (const float*)d_in[4];
    float* out = (float*)d_out;

    const size_t WXT_BYTES = (size_t)N_NODES * EMB * N_NODES * 2;   // 128 MB
    const size_t ATT_BYTES = (size_t)N_NODES * N_NODES * 2;         // 2 MB

    if (ws_size >= WXT_BYTES + ATT_BYTES) {
        unsigned short* wxT = (unsigned short*)d_ws;
        unsigned short* att = (unsigned short*)((char*)d_ws + WXT_BYTES);
        k_wx<<<N_NODES, 256, 0, stream>>>(x, adj, W, a, wxT, att);
        k_out2<<<4096, 256, 0, stream>>>(wxT, att, bias, out);
    } else {
        unsigned short* att = (unsigned short*)d_ws;
        k_att_fb<<<N_NODES, 256, 0, stream>>>(x, adj, W, a, att);
        k_out_fb<<<4096, 256, 0, stream>>>(x, att, W, bias, out);
    }
}

// Round 5
// 769.240 us; speedup vs baseline: 1.2132x; 1.2132x over previous
//
#include <hip/hip_runtime.h>
#include <stdint.h>

#define N_NODES 1024
#define C2v 64
#define EMB 64
#define ALPHA 0.2f
#define NEG_FILL (-1e12f)

typedef __attribute__((ext_vector_type(8))) short short8v;   // 8 bf16 in 4 VGPRs
typedef __attribute__((ext_vector_type(4))) float float4v;
typedef unsigned int u32;

static __device__ __forceinline__ short f2bf(float f) {
    unsigned u = __builtin_bit_cast(unsigned, f);
    u = (u + 0x7FFFu + ((u >> 16) & 1u)) >> 16;   // RNE
    return (short)(unsigned short)u;
}
static __device__ __forceinline__ u32 pack2bf(float a, float b) {
    return (u32)(unsigned short)f2bf(a) | ((u32)(unsigned short)f2bf(b) << 16);
}
static __device__ __forceinline__ void gload16v(const void* g, void* l) {
    __builtin_amdgcn_global_load_lds(
        (const __attribute__((address_space(1))) u32*)g,
        (__attribute__((address_space(3))) u32*)l, 16, 0, 0);
}

// ===========================================================================
// FAST PATH
// k1: wx = x @ W (bf16 MFMA); write wxT[b][e][j] (bf16) to ws; compute
//     s[i,j] = lrelu(wx)·a, masked softmax -> att[i][j] (bf16) to ws.
// vmcnt discipline: steady-state vmcnt(8) drains exactly the previous
// j-tile's 4 loads and leaves the 4 wxT stores + 4 new loads in flight.
// ===========================================================================
__global__ __launch_bounds__(256) void k_wx(const float* __restrict__ x,
                                            const float* __restrict__ adj,
                                            const float* __restrict__ W,
                                            const float* __restrict__ a,
                                            unsigned short* __restrict__ wxT,
                                            unsigned short* __restrict__ att) {
    __shared__ float xs[2][4096];     // 2 x 16KB: per-wave 4KB chunks, swizzled
    __shared__ float s_lds[N_NODES];
    __shared__ float red[8];

    const int i   = blockIdx.x;
    const int tid = threadIdx.x;
    const int w   = tid >> 6;
    const int l   = tid & 63;
    const int g   = l >> 4;
    const int m   = l & 15;

    // W as MFMA B-fragments
    short8v wfrag[4][2];
#pragma unroll
    for (int nt = 0; nt < 4; ++nt)
#pragma unroll
        for (int ks = 0; ks < 2; ++ks) {
            short8v v;
#pragma unroll
            for (int ii = 0; ii < 8; ++ii)
                v[ii] = f2bf(W[(ks * 32 + g * 8 + ii) * EMB + nt * 16 + m]);
            wfrag[nt][ks] = v;
        }
    float afrag[4];
#pragma unroll
    for (int nt = 0; nt < 4; ++nt) afrag[nt] = a[nt * 16 + m];

    const float* xi = x + (size_t)i * N_NODES * C2v;

    // stage j-tile jt into xs[buf]: wave w stages its own rows w*16..w*16+15.
    auto STAGE = [&](int jt, int buf) {
#pragma unroll
        for (int q = 0; q < 4; ++q) {
            const int row  = w * 16 + q * 4 + g;          // row within 64-tile
            const int slot = m ^ (row & 7);               // 16B slot 0..15
            gload16v(xi + (size_t)(jt * 64 + row) * C2v + slot * 4,
                     &xs[buf][w * 1024 + q * 256]);
        }
    };

    STAGE(0, 0);
#pragma unroll
    for (int jt = 0; jt < 16; ++jt) {
        const int buf = jt & 1;
        if (jt < 15) STAGE(jt + 1, buf ^ 1);
        if (jt == 0)      { asm volatile("s_waitcnt vmcnt(4)" ::: "memory"); }
        else if (jt < 15) { asm volatile("s_waitcnt vmcnt(8)" ::: "memory"); }
        else              { asm volatile("s_waitcnt vmcnt(0)" ::: "memory"); }
        __builtin_amdgcn_sched_barrier(0);

        const int j0 = jt * 64 + w * 16;
        float4v acc[4];
#pragma unroll
        for (int nt = 0; nt < 4; ++nt) acc[nt] = (float4v)0.0f;

#pragma unroll
        for (int ks = 0; ks < 2; ++ks) {
            const int slo = (ks * 8 + 2 * g) ^ (m & 7);
            const int shi = (ks * 8 + 2 * g + 1) ^ (m & 7);
            const float4v lo = *(const float4v*)&xs[buf][w * 1024 + m * 64 + slo * 4];
            const float4v hi = *(const float4v*)&xs[buf][w * 1024 + m * 64 + shi * 4];
            short8v afr;
            afr[0] = f2bf(lo[0]); afr[1] = f2bf(lo[1]);
            afr[2] = f2bf(lo[2]); afr[3] = f2bf(lo[3]);
            afr[4] = f2bf(hi[0]); afr[5] = f2bf(hi[1]);
            afr[6] = f2bf(hi[2]); afr[7] = f2bf(hi[3]);
#pragma unroll
            for (int nt = 0; nt < 4; ++nt)
                acc[nt] = __builtin_amdgcn_mfma_f32_16x16x32_bf16(
                    afr, wfrag[nt][ks], acc[nt], 0, 0, 0);
        }

        // wxT[b=i][e=nt*16+m][j0+g*4 .. +3]  (4 consecutive j per lane -> 8B store)
#pragma unroll
        for (int nt = 0; nt < 4; ++nt) {
            uint2 pk;
            pk.x = pack2bf(acc[nt][0], acc[nt][1]);
            pk.y = pack2bf(acc[nt][2], acc[nt][3]);
            *(uint2*)&wxT[((size_t)i * EMB + nt * 16 + m) * N_NODES + j0 + g * 4] = pk;
        }

        // s[j] = sum_e lrelu(wx[j,e]) * a[e]
#pragma unroll
        for (int r = 0; r < 4; ++r) {
            float v = 0.f;
#pragma unroll
            for (int nt = 0; nt < 4; ++nt) {
                float t = acc[nt][r];
                t = (t > 0.f) ? t : (ALPHA * t);
                v += t * afrag[nt];
            }
            v += __shfl_xor(v, 1);
            v += __shfl_xor(v, 2);
            v += __shfl_xor(v, 4);
            v += __shfl_xor(v, 8);
            if (m == 0) s_lds[j0 + g * 4 + r] = v;
        }
    }
    __syncthreads();

    // masked softmax over the 1024 entries
    const float* adjrow = adj + (size_t)i * N_NODES;
    float sc[4];
    float lmax = -3.4e38f;
#pragma unroll
    for (int q = 0; q < 4; ++q) {
        int j = tid + q * 256;
        float v = s_lds[j] + (adjrow[j] > 0.f ? 0.f : NEG_FILL);
        sc[q] = v;
        lmax = fmaxf(lmax, v);
    }
#pragma unroll
    for (int d = 1; d < 64; d <<= 1) lmax = fmaxf(lmax, __shfl_xor(lmax, d));
    if (l == 0) red[w] = lmax;
    __syncthreads();
    const float M = fmaxf(fmaxf(red[0], red[1]), fmaxf(red[2], red[3]));

    float ex[4];
    float lsum = 0.f;
#pragma unroll
    for (int q = 0; q < 4; ++q) {
        ex[q] = __expf(sc[q] - M);
        lsum += ex[q];
    }
#pragma unroll
    for (int d = 1; d < 64; d <<= 1) lsum += __shfl_xor(lsum, d);
    __syncthreads();
    if (l == 0) red[w] = lsum;
    __syncthreads();
    const float S = red[0] + red[1] + red[2] + red[3];
    const float inv = 1.0f / S;

    unsigned short* arow = att + (size_t)i * N_NODES;
#pragma unroll
    for (int q = 0; q < 4; ++q) {
        int j = tid + q * 256;
        arow[j] = (unsigned short)f2bf(ex[q] * inv);
    }
}

// ===========================================================================
// k2 v2: out[b][i][e] = sum_j att[i][j] * wx[b][j][e] + bias[e]
// Per-wave LDS staging of the wxT K-chunk (8KB, double-buffered) via
// global_load_lds with XOR-involution (inverse-swizzled source, swizzled
// ds_read_b128). att fragments prefetched one chunk ahead in registers.
// NO barriers: chunks are wave-private, waves free-run (TLP latency hiding).
// ===========================================================================
__global__ __launch_bounds__(256) void k_out2(const unsigned short* __restrict__ wxT,
                                              const unsigned short* __restrict__ att,
                                              const float* __restrict__ bias,
                                              float* __restrict__ out) {
    __shared__ short wlds[2][4][4096];   // [buf][wave][64 e-rows x 64 j] = 64KB

    const int hw = blockIdx.x;
    const int L  = (hw & 7) * 512 + (hw >> 3);   // XCD swizzle: same-b blocks together
    const int b  = L >> 2;
    const int it = L & 3;

    const int tid = threadIdx.x;
    const int w   = tid >> 6;
    const int l   = tid & 63;
    const int g   = l >> 4;
    const int m   = l & 15;

    const int i0 = it * 256 + w * 64;
    const size_t abase = (size_t)(i0 + m) * N_NODES;          // + mt*16*1024
    const unsigned short* wxb = wxT + (size_t)b * EMB * N_NODES;

    // wave-private stage of wxT[b][e=0..63][kt*64 .. +63] into wlds[buf][w]
    // dest linear (8 instrs x 1KB); source slot pre-swizzled: ss = sd ^ (e&7)
    auto STAGE = [&](int kt, int buf) {
#pragma unroll
        for (int p = 0; p < 8; ++p) {
            const int e  = p * 8 + (l >> 3);
            const int sd = l & 7;
            const int ss = sd ^ (e & 7);
            gload16v(wxb + (size_t)e * N_NODES + kt * 64 + ss * 8,
                     &wlds[buf][w][p * 512]);
        }
    };
    // att fragment loads for chunk kt -> dst[mt][ks]
    auto ATTLOAD = [&](short8v dst[4][2], int kt) {
#pragma unroll
        for (int mt = 0; mt < 4; ++mt)
#pragma unroll
            for (int ks = 0; ks < 2; ++ks)
                dst[mt][ks] = *(const short8v*)&att[abase + (size_t)mt * 16 * N_NODES
                                                   + kt * 64 + ks * 32 + g * 8];
    };

    float4v acc[4][4];
#pragma unroll
    for (int mt = 0; mt < 4; ++mt)
#pragma unroll
        for (int nt = 0; nt < 4; ++nt) acc[mt][nt] = (float4v)0.0f;

    short8v cur[4][2], nxt[4][2];
    STAGE(0, 0);
    ATTLOAD(cur, 0);

#pragma unroll
    for (int kt = 0; kt < 16; ++kt) {
        const int buf = kt & 1;
        if (kt < 15) {
            STAGE(kt + 1, buf ^ 1);
            ATTLOAD(nxt, kt + 1);
            asm volatile("s_waitcnt vmcnt(16)" ::: "memory");  // drain G(kt)+A(kt)
        } else {
            asm volatile("s_waitcnt vmcnt(0)" ::: "memory");
        }
        __builtin_amdgcn_sched_barrier(0);

        const char* base = (const char*)&wlds[buf][w][0];
        __builtin_amdgcn_s_setprio(1);
#pragma unroll
        for (int ks = 0; ks < 2; ++ks) {
            short8v bfr[4];
#pragma unroll
            for (int nt = 0; nt < 4; ++nt) {
                const int e = nt * 16 + m;
                bfr[nt] = *(const short8v*)(base + e * 128 + (((ks * 4 + g) ^ (m & 7)) << 4));
            }
#pragma unroll
            for (int mt = 0; mt < 4; ++mt)
#pragma unroll
                for (int nt = 0; nt < 4; ++nt)
                    acc[mt][nt] = __builtin_amdgcn_mfma_f32_16x16x32_bf16(
                        cur[mt][ks], bfr[nt], acc[mt][nt], 0, 0, 0);
        }
        __builtin_amdgcn_s_setprio(0);

        if (kt < 15) {
#pragma unroll
            for (int mt = 0; mt < 4; ++mt)
#pragma unroll
                for (int ks = 0; ks < 2; ++ks) cur[mt][ks] = nxt[mt][ks];
        }
    }

    float bv[4];
#pragma unroll
    for (int nt = 0; nt < 4; ++nt) bv[nt] = bias[nt * 16 + m];

#pragma unroll
    for (int mt = 0; mt < 4; ++mt)
#pragma unroll
        for (int nt = 0; nt < 4; ++nt)
#pragma unroll
            for (int r = 0; r < 4; ++r) {
                const int i = i0 + mt * 16 + g * 4 + r;
                out[((size_t)b * N_NODES + i) * EMB + nt * 16 + m] = acc[mt][nt][r] + bv[nt];
            }
}

// ===========================================================================
// FALLBACK PATH (ws too small): round-1 kernels, known-correct.
// ===========================================================================
__global__ __launch_bounds__(256) void k_att_fb(const float* __restrict__ x,
                                                const float* __restrict__ adj,
                                                const float* __restrict__ W,
                                                const float* __restrict__ a,
                                                unsigned short* __restrict__ att) {
    __shared__ float s_lds[N_NODES];
    __shared__ float red[8];
    const int i = blockIdx.x, tid = threadIdx.x;
    const int w = tid >> 6, l = tid & 63, g = l >> 4, m = l & 15;
    short8v wfrag[4][2];
#pragma unroll
    for (int nt = 0; nt < 4; ++nt)
#pragma unroll
        for (int ks = 0; ks < 2; ++ks) {
            short8v v;
#pragma unroll
            for (int ii = 0; ii < 8; ++ii)
                v[ii] = f2bf(W[(ks * 32 + g * 8 + ii) * EMB + nt * 16 + m]);
            wfrag[nt][ks] = v;
        }
    float afrag[4];
#pragma unroll
    for (int nt = 0; nt < 4; ++nt) afrag[nt] = a[nt * 16 + m];
    const float* xi = x + (size_t)i * N_NODES * C2v;
    for (int jt = 0; jt < N_NODES / 64; ++jt) {
        const int j0 = jt * 64 + w * 16;
        float4v acc[4];
#pragma unroll
        for (int nt = 0; nt < 4; ++nt) acc[nt] = (float4v)0.0f;
#pragma unroll
        for (int ks = 0; ks < 2; ++ks) {
            const float* p = xi + (size_t)(j0 + m) * C2v + ks * 32 + g * 8;
            float4v lo = *(const float4v*)p;
            float4v hi = *(const float4v*)(p + 4);
            short8v afr;
            afr[0] = f2bf(lo[0]); afr[1] = f2bf(lo[1]);
            afr[2] = f2bf(lo[2]); afr[3] = f2bf(lo[3]);
            afr[4] = f2bf(hi[0]); afr[5] = f2bf(hi[1]);
            afr[6] = f2bf(hi[2]); afr[7] = f2bf(hi[3]);
#pragma unroll
            for (int nt = 0; nt < 4; ++nt)
                acc[nt] = __builtin_amdgcn_mfma_f32_16x16x32_bf16(afr, wfrag[nt][ks], acc[nt], 0, 0, 0);
        }
#pragma unroll
        for (int r = 0; r < 4; ++r) {
            float v = 0.f;
#pragma unroll
            for (int nt = 0; nt < 4; ++nt) {
                float t = acc[nt][r];
                t = (t > 0.f) ? t : (ALPHA * t);
                v += t * afrag[nt];
            }
            v += __shfl_xor(v, 1); v += __shfl_xor(v, 2);
            v += __shfl_xor(v, 4); v += __shfl_xor(v, 8);
            if (m == 0) s_lds[j0 + g * 4 + r] = v;
        }
    }
    __syncthreads();
    const float* adjrow = adj + (size_t)i * N_NODES;
    float sc[4]; float lmax = -3.4e38f;
#pragma unroll
    for (int q = 0; q < 4; ++q) {
        int j = tid + q * 256;
        float v = s_lds[j] + (adjrow[j] > 0.f ? 0.f : NEG_FILL);
        sc[q] = v; lmax = fmaxf(lmax, v);
    }
#pragma unroll
    for (int d = 1; d < 64; d <<= 1) lmax = fmaxf(lmax, __shfl_xor(lmax, d));
    if (l == 0) red[w] = lmax;
    __syncthreads();
    const float M = fmaxf(fmaxf(red[0], red[1]), fmaxf(red[2], red[3]));
    float ex[4]; float lsum = 0.f;
#pragma unroll
    for (int q = 0; q < 4; ++q) { ex[q] = __expf(sc[q] - M); lsum += ex[q]; }
#pragma unroll
    for (int d = 1; d < 64; d <<= 1) lsum += __shfl_xor(lsum, d);
    __syncthreads();
    if (l == 0) red[w] = lsum;
    __syncthreads();
    const float S = red[0] + red[1] + red[2] + red[3];
    const float inv = 1.0f / S;
    unsigned short* arow = att + (size_t)i * N_NODES;
#pragma unroll
    for (int q = 0; q < 4; ++q) {
        int j = tid + q * 256;
        arow[j] = (unsigned short)f2bf(ex[q] * inv);
    }
}

__global__ __launch_bounds__(256) void k_out_fb(const float* __restrict__ x,
                                                const unsigned short* __restrict__ att,
                                                const float* __restrict__ W,
                                                const float* __restrict__ bias,
                                                float* __restrict__ out) {
    __shared__ __attribute__((aligned(16))) short tmp_lds[256][72];
    const int hw = blockIdx.x;
    const int L  = (hw & 7) * 512 + (hw >> 3);
    const int b  = L >> 2;
    const int it = L & 3;
    const int tid = threadIdx.x;
    const int w = tid >> 6, l = tid & 63, g = l >> 4, m = l & 15;
    float4v acc[4][4];
#pragma unroll
    for (int mt = 0; mt < 4; ++mt)
#pragma unroll
        for (int nt = 0; nt < 4; ++nt) acc[mt][nt] = (float4v)0.0f;
    const float* xb = x + (size_t)b * N_NODES * C2v;
    for (int kt = 0; kt < 16; ++kt) {
        const int j0 = kt * 64;
        short8v afr[4][2];
#pragma unroll
        for (int mt = 0; mt < 4; ++mt)
#pragma unroll
            for (int ks = 0; ks < 2; ++ks) {
                const int row = it * 256 + w * 64 + mt * 16 + m;
                afr[mt][ks] = *(const short8v*)&att[(size_t)row * N_NODES + j0 + ks * 32 + g * 8];
            }
        short8v bfr[4][2];
#pragma unroll
        for (int nt = 0; nt < 4; ++nt)
#pragma unroll
            for (int ks = 0; ks < 2; ++ks) {
                short8v v;
#pragma unroll
                for (int ii = 0; ii < 8; ++ii) {
                    const int j = j0 + ks * 32 + g * 8 + ii;
                    v[ii] = f2bf(xb[(size_t)j * C2v + nt * 16 + m]);
                }
                bfr[nt][ks] = v;
            }
#pragma unroll
        for (int mt = 0; mt < 4; ++mt)
#pragma unroll
            for (int nt = 0; nt < 4; ++nt)
#pragma unroll
                for (int ks = 0; ks < 2; ++ks)
                    acc[mt][nt] = __builtin_amdgcn_mfma_f32_16x16x32_bf16(
                        afr[mt][ks], bfr[nt][ks], acc[mt][nt], 0, 0, 0);
    }
#pragma unroll
    for (int mt = 0; mt < 4; ++mt)
#pragma unroll
        for (int nt = 0; nt < 4; ++nt)
#pragma unroll
            for (int r = 0; r < 4; ++r)
                tmp_lds[w * 64 + mt * 16 + g * 4 + r][nt * 16 + m] = f2bf(acc[mt][nt][r]);
    __syncthreads();
    short8v wfrag[4][2];
#pragma unroll
    for (int nt = 0; nt < 4; ++nt)
#pragma unroll
        for (int ks = 0; ks < 2; ++ks) {
            short8v v;
#pragma unroll
            for (int ii = 0; ii < 8; ++ii)
                v[ii] = f2bf(W[(ks * 32 + g * 8 + ii) * EMB + nt * 16 + m]);
            wfrag[nt][ks] = v;
        }
    float bfrag[4];
#pragma unroll
    for (int nt = 0; nt < 4; ++nt) bfrag[nt] = bias[nt * 16 + m];
    float4v acc2[4][4];
#pragma unroll
    for (int mt = 0; mt < 4; ++mt)
#pragma unroll
        for (int nt = 0; nt < 4; ++nt) acc2[mt][nt] = (float4v)0.0f;
#pragma unroll
    for (int mt = 0; mt < 4; ++mt)
#pragma unroll
        for (int ks = 0; ks < 2; ++ks) {
            const short8v a2 = *(const short8v*)&tmp_lds[w * 64 + mt * 16 + m][ks * 32 + g * 8];
#pragma unroll
            for (int nt = 0; nt < 4; ++nt)
                acc2[mt][nt] = __builtin_amdgcn_mfma_f32_16x16x32_bf16(a2, wfrag[nt][ks], acc2[mt][nt], 0, 0, 0);
        }
#pragma unroll
    for (int mt = 0; mt < 4; ++mt)
#pragma unroll
        for (int nt = 0; nt < 4; ++nt)
#pragma unroll
            for (int r = 0; r < 4; ++r) {
                const int i = it * 256 + w * 64 + mt * 16 + g * 4 + r;
                out[((size_t)b * N_NODES + i) * EMB + nt * 16 + m] = acc2[mt][nt][r] + bfrag[nt];
            }
}

extern "C" void kernel_launch(void* const* d_in, const int* in_sizes, int n_in,
                              void* d_out, int out_size, void* d_ws, size_t ws_size,
                              hipStream_t stream) {
    const float* x    = (const float*)d_in[0];
    const float* adj  = (const float*)d_in[1];
    const float* W    = (const float*)d_in[2];
    const float* a    = (const float*)d_in[3];
    const float* bias = (const float*)d_in[4];
    float* out = (float*)d_out;

    const size_t WXT_BYTES = (size_t)N_NODES * EMB * N_NODES * 2;   // 128 MB
    const size_t ATT_BYTES = (size_t)N_NODES * N_NODES * 2;         // 2 MB

    if (ws_size >= WXT_BYTES + ATT_BYTES) {
        unsigned short* wxT = (unsigned short*)d_ws;
        unsigned short* att = (unsigned short*)((char*)d_ws + WXT_BYTES);
        k_wx<<<N_NODES, 256, 0, stream>>>(x, adj, W, a, wxT, att);
        k_out2<<<4096, 256, 0, stream>>>(wxT, att, bias, out);
    } else {
        unsigned short* att = (unsigned short*)d_ws;
        k_att_fb<<<N_NODES, 256, 0, stream>>>(x, adj, W, a, att);
        k_out_fb<<<4096, 256, 0, stream>>>(x, att, W, bias, out);
    }
}